// Round 1
// baseline (145.591 us; speedup 1.0000x reference)
//
#include <hip/hip_runtime.h>
#include <hip/hip_cooperative_groups.h>

namespace cg = cooperative_groups;

#define PP 96
#define NB (PP*PP)            // 9216
#define NCH (NB/64)           // 144 64-chunks
#define PROB_THR 0.9f
#define FAST_CAP 1024         // fast path: M <= 1024, W <= 16
#define LSTRIDE 1034          // padded LDS row stride (u64): even (16B), 2-way max aliasing

typedef unsigned long long u64;
typedef unsigned int u32;

// Bit-identical decode core (no FMA contraction; rintf == round-half-even).
__device__ __forceinline__ void decode_core(int n, float xv, float yv, float wv, float hv,
                                            float& X1, float& Y1, float& X2, float& Y2)
{
    int i = n / PP;
    int j = n - i * PP;
    float bx = __fadd_rn(__fmul_rn(xv, 16.0f), (float)i * 16.0f);
    float by = __fadd_rn(__fmul_rn(yv, 16.0f), (float)j * 16.0f);
    float bw = __fmul_rn(wv, 1536.0f);
    float bh = __fmul_rn(hv, 1536.0f);
    X1 = rintf(bx);
    Y1 = rintf(by);
    X2 = rintf(__fadd_rn(bw, bx));
    Y2 = rintf(__fadd_rn(bh, by));
}

__device__ __forceinline__ void decode_box(const float* __restrict__ x, int n,
                                           float& X1, float& Y1, float& X2, float& Y2)
{
    decode_core(n, x[NB + n], x[2 * NB + n], x[3 * NB + n], x[4 * NB + n], X1, Y1, X2, Y2);
}

// Exact-equivalent IoU>0.5 without division (R5-R10 validated on HW).
__device__ __forceinline__ int iou_hit_nodiv(float ix1, float iy1, float ix2, float iy2, float iar,
                                             float jx1, float jy1, float jx2, float jy2, float jar)
{
    float xx1 = fmaxf(ix1, jx1), yy1 = fmaxf(iy1, jy1);
    float xx2 = fminf(ix2, jx2), yy2 = fminf(iy2, jy2);
    float iw = fmaxf(__fsub_rn(xx2, xx1), 0.0f);
    float ih = fmaxf(__fsub_rn(yy2, yy1), 0.0f);
    float inter = __fmul_rn(iw, ih);
    float uni = __fsub_rn(__fadd_rn(iar, jar), inter);
    return (uni > 0.0f && __fadd_rn(inter, inter) > uni) ? 1 : 0;
}

__device__ __forceinline__ int iou_hit_div(float ix1, float iy1, float ix2, float iy2, float iar,
                                           float jx1, float jy1, float jx2, float jy2, float jar)
{
    float xx1 = fmaxf(ix1, jx1), yy1 = fmaxf(iy1, jy1);
    float xx2 = fminf(ix2, jx2), yy2 = fminf(iy2, jy2);
    float iw = fmaxf(__fsub_rn(xx2, xx1), 0.0f);
    float ih = fmaxf(__fsub_rn(yy2, yy1), 0.0f);
    float inter = __fmul_rn(iw, ih);
    float uni = __fsub_rn(__fadd_rn(iar, jar), inter);
    return (uni > 0.0f && __fdiv_rn(inter, uni) > 0.5f) ? 1 : 0;
}

// ---------------------------------------------------------------------------
// Fused cooperative kernel, 64 blocks x 256.
// Phase A: blocks 0-15 = k_sort (R10-validated logic, unchanged); blocks
//          16-63 concurrently zero `out` (was on k_adj's critical path).
// grid.sync()
// Phase B: all 64 blocks = k_adj adjacency build (logic unchanged).
// grid.sync()
// Phase C: block 0 = k_sweep (logic unchanged) + emit.
// LDS for the three phases is union'd (max 133,504 B <= 160 KiB).
// ---------------------------------------------------------------------------
__global__ void __launch_bounds__(256, 1) k_fused(
    const float* __restrict__ x, float* __restrict__ out,
    float* __restrict__ gss, float4* __restrict__ gbox,
    u64* __restrict__ skeys, int* __restrict__ counter,
    u64* __restrict__ adjT, int ws_ok)
{
    cg::grid_group grid = cg::this_grid();

    __shared__ __align__(16) union ShU {
        struct {                                   // phase A (k_sort)
            u64 lmask[NCH]; int pc[NCH]; int loff[NCH]; int sM;
            u64 kdb[FAST_CAP]; int prank[256];
        } a;
        struct {                                   // phase B (k_adj)
            float4 lb[FAST_CAP]; float la[FAST_CAP];
        } p2;
        struct {                                   // phase C (k_sweep)
            u64 Lds[16 * LSTRIDE]; u64 keepw[NCH];
        } p3;
    } sh;

    const int tid = threadIdx.x;
    const int lane = tid & 63;
    const int wv = tid >> 6;
    const int b = blockIdx.x;

    // ===================== Phase A =====================
    if (b < 16) {
        #pragma unroll
        for (int g = 0; g < 36; g += 6) {
            float sv[6];
            #pragma unroll
            for (int u = 0; u < 6; ++u)
                sv[u] = x[((wv * 36 + g + u) << 6) + lane];
            #pragma unroll
            for (int u = 0; u < 6; ++u) {
                u64 m = __ballot(sv[u] > PROB_THR);
                if (lane == 0) sh.a.lmask[wv * 36 + g + u] = m;
            }
        }
        __syncthreads();
        if (tid < NCH) sh.a.pc[tid] = __popcll(sh.a.lmask[tid]);
        __syncthreads();
        if (tid < 64) {                           // wave-parallel prefix (validated)
            int acc = 0;
            for (int seg = 0; seg < 3; ++seg) {
                int c = (seg << 6) + lane;
                int pv = (c < NCH) ? sh.a.pc[c] : 0;
                int v = pv;
                #pragma unroll
                for (int off = 1; off < 64; off <<= 1) {
                    int u = __shfl_up(v, off);
                    if (lane >= off) v += u;
                }
                if (c < NCH) sh.a.loff[c] = acc + v - pv;
                acc += __shfl(v, 63);
            }
            if (lane == 0) sh.a.sM = acc;
        }
        __syncthreads();
        const int Ma = sh.a.sM;
        const bool fasta = (Ma <= FAST_CAP) && ws_ok;
        if (b == 0 && tid == 0) counter[0] = Ma;

        if (!fasta) {
            if (b == 0) {
                for (int c = wv; c < NCH; c += 4) {
                    float s = x[(c << 6) + lane];
                    u64 m = sh.a.lmask[c];
                    if ((m >> lane) & 1ull) {
                        int pos = sh.a.loff[c] + __popcll(m & ((1ull << lane) - 1ull));
                        int n = (c << 6) + lane;
                        skeys[pos] = ((u64)__float_as_uint(s) << 32) | (u64)(NB - 1 - n);
                    }
                }
            }
        } else {
            for (int c = wv; c < NCH; c += 4) {
                float s = x[(c << 6) + lane];      // L1-warm
                u64 m = sh.a.lmask[c];
                if ((m >> lane) & 1ull) {
                    int pos = sh.a.loff[c] + __popcll(m & ((1ull << lane) - 1ull));
                    int n = (c << 6) + lane;
                    sh.a.kdb[pos] = ((u64)__float_as_uint(s) << 32) | (u64)(NB - 1 - n);
                }
            }
            for (int q = Ma + tid; q < FAST_CAP; q += 256) sh.a.kdb[q] = 0ull;  // pad
            __syncthreads();

            const int cand = (b << 6) + lane;      // < 1024 always
            const u64 k0 = sh.a.kdb[cand];
            const int n0 = NB - 1 - (int)(k0 & 0xFFFFFFFFull);
            float xv0 = x[NB + n0], yv0 = x[2 * NB + n0];
            float wv0 = x[3 * NB + n0], hv0 = x[4 * NB + n0];
            int r = 0;
            const int nck = (Ma + 63) >> 6;
            for (int ch = wv; ch < nck; ch += 4) { // wave-uniform chunk slice
                u64 kq = sh.a.kdb[(ch << 6) + lane];
                u32 qlo = (u32)kq, qhi = (u32)(kq >> 32);
                #pragma unroll
                for (int i = 0; i < 64; ++i) {
                    u32 blo = (u32)__builtin_amdgcn_readlane((int)qlo, i);
                    u32 bhi = (u32)__builtin_amdgcn_readlane((int)qhi, i);
                    u64 kb = ((u64)bhi << 32) | (u64)blo;
                    r += (kb > k0) ? 1 : 0;
                }
            }
            sh.a.prank[tid] = r;
            __syncthreads();
            if (tid < 64 && cand < Ma) {
                int rk = sh.a.prank[tid] + sh.a.prank[64 + tid]
                       + sh.a.prank[128 + tid] + sh.a.prank[192 + tid];
                float X1, Y1, X2, Y2;
                decode_core(n0, xv0, yv0, wv0, hv0, X1, Y1, X2, Y2);
                gbox[rk] = make_float4(X1, Y1, X2, Y2);
                gss[rk] = __uint_as_float((u32)(k0 >> 32));
            }
        }
    } else {
        // blocks 16-63: zero the whole out buffer (48 blocks x 288 float4
        // = 64*216 float4 total), concurrent with the sort.
        float4 z4 = make_float4(0.f, 0.f, 0.f, 0.f);
        const int base = (b - 16) * 288;
        for (int q = tid; q < 288; q += 256)
            ((float4*)out)[base + q] = z4;
    }
    __threadfence();
    grid.sync();

    int M = *(volatile int*)counter; if (M > NB) M = NB;
    const bool fast = (M <= FAST_CAP) && ws_ok;

    // ===================== Phase B =====================
    if (fast && ((b << 4) < M)) {
        const int W = (M + 63) >> 6;
        for (int f = tid; f < M; f += 256) {
            float4 bb = gbox[f];
            sh.p2.lb[f] = bb;
            sh.p2.la[f] = __fmul_rn(__fsub_rn(bb.z, bb.x), __fsub_rn(bb.w, bb.y));
        }
        __syncthreads();

        #pragma unroll
        for (int r = 0; r < 4; ++r) {
            int i = (b << 4) + (r << 2) + wv;
            if (i >= M) break;
            float4 bi = sh.p2.lb[i];
            float iar = sh.p2.la[i];
            for (int kk = 0; kk < W; ++kk) {
                int j = (kk << 6) + lane;
                float4 bj = sh.p2.lb[j & (FAST_CAP - 1)];
                float jar = sh.p2.la[j & (FAST_CAP - 1)];
                int hit = (j < M) && iou_hit_nodiv(bi.x, bi.y, bi.z, bi.w, iar,
                                                   bj.x, bj.y, bj.z, bj.w, jar);
                u64 mm = __ballot(hit);
                if (lane == 0) adjT[((size_t)kk << 10) + i] = mm;
            }
        }
    }
    __threadfence();
    grid.sync();

    // ===================== Phase C =====================
    if (b != 0) return;

    const int W = (M + 63) >> 6;
    if (fast) {
        // ---- stage adjT -> LDS: 4 rounds x 8-deep batched 16B (R9-validated) ----
        const int npair = W << 9;                 // <= 8192 ulonglong2
        const ulonglong2* gp = (const ulonglong2*)adjT;
        for (int r = 0; r < 4; ++r) {
            int fb = (r << 11) + tid;
            ulonglong2 v[8];
            #pragma unroll
            for (int u = 0; u < 8; ++u) {
                int f = fb + (u << 8);
                v[u] = (f < npair) ? gp[f] : make_ulonglong2(0ull, 0ull);
            }
            #pragma unroll
            for (int u = 0; u < 8; ++u) {
                int f = fb + (u << 8);
                if (f < npair) {
                    int w = f >> 9, r2 = f & 511;
                    ((ulonglong2*)sh.p3.Lds)[w * (LSTRIDE >> 1) + r2] = v[u];
                }
            }
        }
        __syncthreads();

        if (tid < 64) {
            const int wl = (lane < W) ? lane : 0;
            u32 supl = 0u, suph = 0u, dl = 0u, dh = 0u;
            u64 mykw = 0ull;
            const int nrb = (M + 31) >> 5;
            for (int rb = 0; rb < nrb; ++rb) {
                const int c = rb >> 1;
                const int base = rb << 5;
                const ulonglong2* crow = (const ulonglong2*)(sh.p3.Lds + (size_t)c * LSTRIDE + base);
                const ulonglong2* rrow = (const ulonglong2*)(sh.p3.Lds + (size_t)wl * LSTRIDE + base);
                // batch-issue BOTH columns as 32 independent b128 reads -> regs
                u64 colb[32], rowb[32];
                #pragma unroll
                for (int q = 0; q < 16; ++q) {
                    ulonglong2 t2 = crow[q];
                    colb[2 * q] = t2.x; colb[2 * q + 1] = t2.y;
                }
                #pragma unroll
                for (int q = 0; q < 16; ++q) {
                    ulonglong2 t2 = rrow[q];
                    rowb[2 * q] = t2.x; rowb[2 * q + 1] = t2.y;
                }
                if (!(rb & 1)) {
                    if (rb == 0) { dl = 0u; dh = 0u; }
                    else { dl = (u32)__shfl((int)supl, c); dh = (u32)__shfl((int)suph, c); }
                    int rem = M - (c << 6);       // tail: rows >= M suppressed
                    if (rem < 64) {
                        if (rem >= 32) dh |= 0xFFFFFFFFu << (rem - 32);
                        else { dh = 0xFFFFFFFFu; dl |= 0xFFFFFFFFu << rem; }
                    }
                }
                u32 kw = 0u;
                if (!(rb & 1)) {
                    #pragma unroll
                    for (int t = 0; t < 32; ++t) {
                        u32 bbit = (dl >> t) & 1u;
                        u32 m = bbit - 1u;        // ~0 kept, 0 suppressed
                        dl |= (u32)colb[t] & m;
                        dh |= (u32)(colb[t] >> 32) & m;
                        kw |= m & (1u << t);
                    }
                } else {
                    #pragma unroll
                    for (int t = 0; t < 32; ++t) {
                        u32 bbit = (dh >> t) & 1u;
                        u32 m = bbit - 1u;
                        dl |= (u32)colb[t] & m;
                        dh |= (u32)(colb[t] >> 32) & m;
                        kw |= m & (1u << t);
                    }
                }
                // constant-trip masked suppression-OR (values already in regs)
                #pragma unroll
                for (int t = 0; t < 32; ++t) {
                    u32 m = 0u - ((kw >> t) & 1u);  // ~0 if kept
                    supl |= (u32)rowb[t] & m;
                    suph |= (u32)(rowb[t] >> 32) & m;
                }
                mykw |= (lane == c) ? ((u64)kw << ((rb & 1) << 5)) : 0ull;
            }
            sh.p3.keepw[lane] = mykw;
        }
    } else {
        // slow path (M > 1024): counting rank + decode + single-wave sweep.
        for (int t = tid; t < M; t += 256) {
            u64 key = skeys[t];
            int r = 0;
            for (int q = 0; q < M; ++q) r += (skeys[q] > key) ? 1 : 0;
            int n = NB - 1 - (int)(key & 0xFFFFFFFFull);
            float X1, Y1, X2, Y2;
            decode_box(x, n, X1, Y1, X2, Y2);
            gbox[r] = make_float4(X1, Y1, X2, Y2);
            gss[r] = __uint_as_float((u32)(key >> 32));
        }
        __threadfence();
        __syncthreads();
        if (tid < 64) {
            u64 kbs[3] = {0ull, 0ull, 0ull};
            for (int i = 0; i < M; ++i) {
                float4 bi = gbox[i];
                float iar = __fmul_rn(__fsub_rn(bi.z, bi.x), __fsub_rn(bi.w, bi.y));
                int hit = 0;
                int nk = (i > lane) ? ((i - lane + 63) >> 6) : 0;
                for (int w = 0; w < 3 && !hit; ++w) {
                    int klim = nk - (w << 6);
                    if (klim <= 0) break;
                    u64 bits = kbs[w];
                    if (klim < 64) bits &= ((1ull << klim) - 1ull);
                    while (bits) {
                        int kk2 = __builtin_ctzll(bits);
                        bits &= bits - 1ull;
                        int jj = lane + (((w << 6) + kk2) << 6);
                        float4 bj = gbox[jj];
                        float jar = __fmul_rn(__fsub_rn(bj.z, bj.x), __fsub_rn(bj.w, bj.y));
                        if (iou_hit_div(bi.x, bi.y, bi.z, bi.w, iar,
                                        bj.x, bj.y, bj.z, bj.w, jar)) { hit = 1; break; }
                    }
                }
                int suppressed = __any(hit);
                if (!suppressed && lane == (i & 63)) kbs[(i >> 6) >> 6] |= 1ull << ((i >> 6) & 63);
            }
            int NWrd = (M + 63) >> 6;
            for (int wd = 0; wd < NWrd; ++wd) {
                u64 bit = (kbs[wd >> 6] >> (wd & 63)) & 1ull;
                u64 word = __ballot(bit != 0);
                if (lane == 0 && wd < NCH) sh.p3.keepw[wd] = word;
            }
        }
    }
    __syncthreads();

    // emit kept rows only (rest pre-zeroed in phase A)
    for (int i = tid; i < M; i += 256) {
        if ((sh.p3.keepw[i >> 6] >> (i & 63)) & 1ull) {
            float4 bb = gbox[i];
            out[i * 5 + 0] = gss[i];
            out[i * 5 + 1] = bb.x;
            out[i * 5 + 2] = bb.y;
            out[i * 5 + 3] = __fsub_rn(bb.z, bb.x);
            out[i * 5 + 4] = __fsub_rn(bb.w, bb.y);
            out[5 * NB + i] = 1.0f;
        }
    }
}

extern "C" void kernel_launch(void* const* d_in, const int* in_sizes, int n_in,
                              void* d_out, int out_size, void* d_ws, size_t ws_size,
                              hipStream_t stream) {
    const float* x = (const float*)d_in[0];
    float* out = (float*)d_out;

    char* ws = (char*)d_ws;
    int* counter = (int*)ws;
    float*  gss  = (float*)(ws + 16);
    float4* gbox = (float4*)(ws + 16 + (size_t)4 * NB);
    u64*    adjT = (u64*)(ws + 16 + (size_t)4 * NB + (size_t)16 * NB);
    u64*    skeys = (u64*)((char*)adjT + (size_t)16384 * 8);
    const size_t NEEDED = 16 + (size_t)4 * NB + (size_t)16 * NB
                        + (size_t)16384 * 8 + (size_t)8 * NB;      // 389,136
    int ws_ok = (ws_size >= NEEDED) ? 1 : 0;

    void* kargs[] = { (void*)&x, (void*)&out, (void*)&gss, (void*)&gbox,
                      (void*)&skeys, (void*)&counter, (void*)&adjT, (void*)&ws_ok };
    hipLaunchCooperativeKernel(reinterpret_cast<void*>(&k_fused),
                               dim3(64), dim3(256), kargs, 0, stream);
}

// Round 2
// 120.127 us; speedup vs baseline: 1.2120x; 1.2120x over previous
//
#include <hip/hip_runtime.h>

#define PP 96
#define NB (PP*PP)            // 9216
#define NCH (NB/64)           // 144 64-chunks
#define PROB_THR 0.9f
#define FAST_CAP 1024         // fast path: M <= 1024, W <= 16
#define LSTRIDE 1034          // padded LDS row stride (u64): even (16B), 2-way max aliasing

typedef unsigned long long u64;
typedef unsigned int u32;

// Bit-identical decode core (no FMA contraction; rintf == round-half-even).
__device__ __forceinline__ void decode_core(int n, float xv, float yv, float wv, float hv,
                                            float& X1, float& Y1, float& X2, float& Y2)
{
    int i = n / PP;
    int j = n - i * PP;
    float bx = __fadd_rn(__fmul_rn(xv, 16.0f), (float)i * 16.0f);
    float by = __fadd_rn(__fmul_rn(yv, 16.0f), (float)j * 16.0f);
    float bw = __fmul_rn(wv, 1536.0f);
    float bh = __fmul_rn(hv, 1536.0f);
    X1 = rintf(bx);
    Y1 = rintf(by);
    X2 = rintf(__fadd_rn(bw, bx));
    Y2 = rintf(__fadd_rn(bh, by));
}

__device__ __forceinline__ void decode_box(const float* __restrict__ x, int n,
                                           float& X1, float& Y1, float& X2, float& Y2)
{
    decode_core(n, x[NB + n], x[2 * NB + n], x[3 * NB + n], x[4 * NB + n], X1, Y1, X2, Y2);
}

// Exact-equivalent IoU>0.5 without division (R5-R10 validated on HW).
__device__ __forceinline__ int iou_hit_nodiv(float ix1, float iy1, float ix2, float iy2, float iar,
                                             float jx1, float jy1, float jx2, float jy2, float jar)
{
    float xx1 = fmaxf(ix1, jx1), yy1 = fmaxf(iy1, jy1);
    float xx2 = fminf(ix2, jx2), yy2 = fminf(iy2, jy2);
    float iw = fmaxf(__fsub_rn(xx2, xx1), 0.0f);
    float ih = fmaxf(__fsub_rn(yy2, yy1), 0.0f);
    float inter = __fmul_rn(iw, ih);
    float uni = __fsub_rn(__fadd_rn(iar, jar), inter);
    return (uni > 0.0f && __fadd_rn(inter, inter) > uni) ? 1 : 0;
}

__device__ __forceinline__ int iou_hit_div(float ix1, float iy1, float ix2, float iy2, float iar,
                                           float jx1, float jy1, float jx2, float jy2, float jar)
{
    float xx1 = fmaxf(ix1, jx1), yy1 = fmaxf(iy1, jy1);
    float xx2 = fminf(ix2, jx2), yy2 = fminf(iy2, jy2);
    float iw = fmaxf(__fsub_rn(xx2, xx1), 0.0f);
    float ih = fmaxf(__fsub_rn(yy2, yy1), 0.0f);
    float inter = __fmul_rn(iw, ih);
    float uni = __fsub_rn(__fadd_rn(iar, jar), inter);
    return (uni > 0.0f && __fdiv_rn(inter, uni) > 0.5f) ? 1 : 0;
}

// ---------------------------------------------------------------------------
// Dispatch 1: k_front, 64 blocks x 256 — fused sort + adjacency.
// Every block redundantly builds the full candidate set (as the old k_sort
// already did), ranks ALL 1024 slots (4 cands/thread, validated readlane
// compare), scatters decoded boxes+areas to LDS by rank, then runs the old
// k_adj ballot loop for its 16 rows straight out of LDS. Block 0 also writes
// gbox/gss (sorted) for the sweep's emit. Removes one dispatch boundary and
// the gbox global round-trip (R1 theory: boundaries ~27 us each dominate).
// ---------------------------------------------------------------------------
__global__ void __launch_bounds__(256) k_front(
    const float* __restrict__ x,
    float* __restrict__ gss, float4* __restrict__ gbox,
    u64* __restrict__ skeys, int* __restrict__ counter,
    u64* __restrict__ adjT, int ws_ok)
{
    __shared__ u64 lmask[NCH];
    __shared__ int pc[NCH], loff[NCH];
    __shared__ int sM;
    __shared__ u64 kdb[FAST_CAP];
    __shared__ float4 lb[FAST_CAP];
    __shared__ float la[FAST_CAP];

    const int tid = threadIdx.x;
    const int lane = tid & 63;
    const int wv = tid >> 6;                  // 4 waves; 36 chunks each
    const int b = blockIdx.x;

    #pragma unroll
    for (int g = 0; g < 36; g += 6) {
        float sv[6];
        #pragma unroll
        for (int u = 0; u < 6; ++u)
            sv[u] = x[((wv * 36 + g + u) << 6) + lane];
        #pragma unroll
        for (int u = 0; u < 6; ++u) {
            u64 m = __ballot(sv[u] > PROB_THR);
            if (lane == 0) lmask[wv * 36 + g + u] = m;
        }
    }
    __syncthreads();
    if (tid < NCH) pc[tid] = __popcll(lmask[tid]);
    __syncthreads();
    if (tid < 64) {                           // wave-parallel prefix (validated)
        int acc = 0;
        for (int seg = 0; seg < 3; ++seg) {
            int c = (seg << 6) + lane;
            int pv = (c < NCH) ? pc[c] : 0;
            int v = pv;
            #pragma unroll
            for (int off = 1; off < 64; off <<= 1) {
                int u = __shfl_up(v, off);
                if (lane >= off) v += u;
            }
            if (c < NCH) loff[c] = acc + v - pv;
            acc += __shfl(v, 63);
        }
        if (lane == 0) sM = acc;
    }
    __syncthreads();
    const int M = sM;
    const bool fast = (M <= FAST_CAP) && ws_ok;
    if (b == 0 && tid == 0) counter[0] = M;

    if (!fast) {
        if (b == 0) {
            for (int c = wv; c < NCH; c += 4) {
                float s = x[(c << 6) + lane];
                u64 m = lmask[c];
                if ((m >> lane) & 1ull) {
                    int pos = loff[c] + __popcll(m & ((1ull << lane) - 1ull));
                    int n = (c << 6) + lane;
                    skeys[pos] = ((u64)__float_as_uint(s) << 32) | (u64)(NB - 1 - n);
                }
            }
        }
        return;
    }
    // blocks with an empty adjacency slice (and no side outputs) exit early
    if (b != 0 && (b << 4) >= M) return;

    for (int c = wv; c < NCH; c += 4) {
        float s = x[(c << 6) + lane];          // L1-warm
        u64 m = lmask[c];
        if ((m >> lane) & 1ull) {
            int pos = loff[c] + __popcll(m & ((1ull << lane) - 1ull));
            int n = (c << 6) + lane;
            kdb[pos] = ((u64)__float_as_uint(s) << 32) | (u64)(NB - 1 - n);
        }
    }
    for (int q = M + tid; q < FAST_CAP; q += 256) kdb[q] = 0ull;  // pad
    __syncthreads();

    // ---- rank ALL 1024 slots: 4 candidates per thread ----
    u64 k0v[4]; int rkv[4]; int n0v[4];
    float xvv[4], yvv[4], wvv[4], hvv[4];
    #pragma unroll
    for (int g = 0; g < 4; ++g) {
        k0v[g] = kdb[(g << 8) + tid];
        rkv[g] = 0;
        n0v[g] = NB - 1 - (int)(k0v[g] & 0xFFFFFFFFull);
        // prefetch box channels (safe addr even for padded slots); hides
        // the gather latency under the rank loop below.
        xvv[g] = x[NB + n0v[g]];
        yvv[g] = x[2 * NB + n0v[g]];
        wvv[g] = x[3 * NB + n0v[g]];
        hvv[g] = x[4 * NB + n0v[g]];
    }
    const int nck = (M + 63) >> 6;
    for (int ch = 0; ch < nck; ++ch) {
        u64 kq = kdb[(ch << 6) + lane];
        u32 qlo = (u32)kq, qhi = (u32)(kq >> 32);
        #pragma unroll
        for (int i = 0; i < 64; ++i) {
            u32 blo = (u32)__builtin_amdgcn_readlane((int)qlo, i);
            u32 bhi = (u32)__builtin_amdgcn_readlane((int)qhi, i);
            u64 kb = ((u64)bhi << 32) | (u64)blo;
            #pragma unroll
            for (int g = 0; g < 4; ++g)
                rkv[g] += (kb > k0v[g]) ? 1 : 0;
        }
    }

    // ---- decode + scatter sorted boxes/areas into LDS (and global, b==0) ----
    #pragma unroll
    for (int g = 0; g < 4; ++g) {
        int cand = (g << 8) + tid;
        if (cand < M) {
            float X1, Y1, X2, Y2;
            decode_core(n0v[g], xvv[g], yvv[g], wvv[g], hvv[g], X1, Y1, X2, Y2);
            float4 bb = make_float4(X1, Y1, X2, Y2);
            int rk = rkv[g];
            lb[rk] = bb;
            la[rk] = __fmul_rn(__fsub_rn(X2, X1), __fsub_rn(Y2, Y1));
            if (b == 0) {
                gbox[rk] = bb;
                gss[rk] = __uint_as_float((u32)(k0v[g] >> 32));
            }
        }
    }
    __syncthreads();

    // ---- adjacency slice (old k_adj body, LDS-direct) ----
    const int W = (M + 63) >> 6;
    #pragma unroll
    for (int r = 0; r < 4; ++r) {
        int i = (b << 4) + (r << 2) + wv;
        if (i >= M) break;
        float4 bi = lb[i];
        float iar = la[i];
        for (int kk = 0; kk < W; ++kk) {
            int j = (kk << 6) + lane;
            float4 bj = lb[j & (FAST_CAP - 1)];
            float jar = la[j & (FAST_CAP - 1)];
            int hit = (j < M) && iou_hit_nodiv(bi.x, bi.y, bi.z, bi.w, iar,
                                               bj.x, bj.y, bj.z, bj.w, jar);
            u64 mm = __ballot(hit);
            if (lane == 0) adjT[((size_t)kk << 10) + i] = mm;
        }
    }
}

// ---------------------------------------------------------------------------
// Dispatch 2: k_sweep, 1 block x 256 (validated R10 structure), with the
// out-zeroing folded in as fire-and-forget stores at the top (drained by the
// existing barriers before emit).
// ---------------------------------------------------------------------------
__global__ void __launch_bounds__(256) k_sweep(
    const float* __restrict__ x, float* __restrict__ out,
    float* __restrict__ gss, float4* __restrict__ gbox,
    const u64* __restrict__ skeys, const int* __restrict__ counter,
    const u64* __restrict__ adjT, int ws_ok)
{
    __shared__ __align__(16) u64 Lds[16 * LSTRIDE];   // 132,352 B
    __shared__ u64 keepw[NCH];

    const int tid = threadIdx.x, lane = tid & 63;

    // zero the whole out buffer (6*NB floats = 13824 float4); fire-and-forget
    {
        float4 z4 = make_float4(0.f, 0.f, 0.f, 0.f);
        for (int q = tid; q < 13824; q += 256)
            ((float4*)out)[q] = z4;
    }

    int M = counter[0]; if (M > NB) M = NB;
    const int W = (M + 63) >> 6;
    const bool fast = (M <= FAST_CAP) && ws_ok;

    if (fast) {
        // ---- stage adjT -> LDS: 4 rounds x 8-deep batched 16B (R9-validated) ----
        const int npair = W << 9;                     // <= 8192 ulonglong2
        const ulonglong2* gp = (const ulonglong2*)adjT;
        for (int r = 0; r < 4; ++r) {
            int fb = (r << 11) + tid;
            ulonglong2 v[8];
            #pragma unroll
            for (int u = 0; u < 8; ++u) {
                int f = fb + (u << 8);
                v[u] = (f < npair) ? gp[f] : make_ulonglong2(0ull, 0ull);
            }
            #pragma unroll
            for (int u = 0; u < 8; ++u) {
                int f = fb + (u << 8);
                if (f < npair) {
                    int w = f >> 9, r2 = f & 511;
                    ((ulonglong2*)Lds)[w * (LSTRIDE >> 1) + r2] = v[u];
                }
            }
        }
        __syncthreads();

        if (tid < 64) {
            const int wl = (lane < W) ? lane : 0;
            u32 supl = 0u, suph = 0u, dl = 0u, dh = 0u;
            u64 mykw = 0ull;
            const int nrb = (M + 31) >> 5;
            for (int rb = 0; rb < nrb; ++rb) {
                const int c = rb >> 1;
                const int base = rb << 5;
                const ulonglong2* crow = (const ulonglong2*)(Lds + (size_t)c * LSTRIDE + base);
                const ulonglong2* rrow = (const ulonglong2*)(Lds + (size_t)wl * LSTRIDE + base);
                // batch-issue BOTH columns as 32 independent b128 reads -> regs
                u64 colb[32], rowb[32];
                #pragma unroll
                for (int q = 0; q < 16; ++q) {
                    ulonglong2 t2 = crow[q];
                    colb[2 * q] = t2.x; colb[2 * q + 1] = t2.y;
                }
                #pragma unroll
                for (int q = 0; q < 16; ++q) {
                    ulonglong2 t2 = rrow[q];
                    rowb[2 * q] = t2.x; rowb[2 * q + 1] = t2.y;
                }
                if (!(rb & 1)) {
                    if (rb == 0) { dl = 0u; dh = 0u; }
                    else { dl = (u32)__shfl((int)supl, c); dh = (u32)__shfl((int)suph, c); }
                    int rem = M - (c << 6);           // tail: rows >= M suppressed
                    if (rem < 64) {
                        if (rem >= 32) dh |= 0xFFFFFFFFu << (rem - 32);
                        else { dh = 0xFFFFFFFFu; dl |= 0xFFFFFFFFu << rem; }
                    }
                }
                u32 kw = 0u;
                if (!(rb & 1)) {
                    #pragma unroll
                    for (int t = 0; t < 32; ++t) {
                        u32 bbit = (dl >> t) & 1u;
                        u32 m = bbit - 1u;            // ~0 kept, 0 suppressed
                        dl |= (u32)colb[t] & m;
                        dh |= (u32)(colb[t] >> 32) & m;
                        kw |= m & (1u << t);
                    }
                } else {
                    #pragma unroll
                    for (int t = 0; t < 32; ++t) {
                        u32 bbit = (dh >> t) & 1u;
                        u32 m = bbit - 1u;
                        dl |= (u32)colb[t] & m;
                        dh |= (u32)(colb[t] >> 32) & m;
                        kw |= m & (1u << t);
                    }
                }
                // constant-trip masked suppression-OR (values already in regs)
                #pragma unroll
                for (int t = 0; t < 32; ++t) {
                    u32 m = 0u - ((kw >> t) & 1u);    // ~0 if kept
                    supl |= (u32)rowb[t] & m;
                    suph |= (u32)(rowb[t] >> 32) & m;
                }
                mykw |= (lane == c) ? ((u64)kw << ((rb & 1) << 5)) : 0ull;
            }
            keepw[lane] = mykw;
        }
    } else {
        // slow path (M > 1024): counting rank + decode + single-wave sweep.
        for (int t = tid; t < M; t += 256) {
            u64 key = skeys[t];
            int r = 0;
            for (int q = 0; q < M; ++q) r += (skeys[q] > key) ? 1 : 0;
            int n = NB - 1 - (int)(key & 0xFFFFFFFFull);
            float X1, Y1, X2, Y2;
            decode_box(x, n, X1, Y1, X2, Y2);
            gbox[r] = make_float4(X1, Y1, X2, Y2);
            gss[r] = __uint_as_float((u32)(key >> 32));
        }
        __threadfence();
        __syncthreads();
        if (tid < 64) {
            u64 kbs[3] = {0ull, 0ull, 0ull};
            for (int i = 0; i < M; ++i) {
                float4 bi = gbox[i];
                float iar = __fmul_rn(__fsub_rn(bi.z, bi.x), __fsub_rn(bi.w, bi.y));
                int hit = 0;
                int nk = (i > lane) ? ((i - lane + 63) >> 6) : 0;
                for (int w = 0; w < 3 && !hit; ++w) {
                    int klim = nk - (w << 6);
                    if (klim <= 0) break;
                    u64 bits = kbs[w];
                    if (klim < 64) bits &= ((1ull << klim) - 1ull);
                    while (bits) {
                        int kk2 = __builtin_ctzll(bits);
                        bits &= bits - 1ull;
                        int jj = lane + (((w << 6) + kk2) << 6);
                        float4 bj = gbox[jj];
                        float jar = __fmul_rn(__fsub_rn(bj.z, bj.x), __fsub_rn(bj.w, bj.y));
                        if (iou_hit_div(bi.x, bi.y, bi.z, bi.w, iar,
                                        bj.x, bj.y, bj.z, bj.w, jar)) { hit = 1; break; }
                    }
                }
                int suppressed = __any(hit);
                if (!suppressed && lane == (i & 63)) kbs[(i >> 6) >> 6] |= 1ull << ((i >> 6) & 63);
            }
            int NWrd = (M + 63) >> 6;
            for (int wd = 0; wd < NWrd; ++wd) {
                u64 bit = (kbs[wd >> 6] >> (wd & 63)) & 1ull;
                u64 word = __ballot(bit != 0);
                if (lane == 0 && wd < NCH) keepw[wd] = word;
            }
        }
    }
    __syncthreads();

    // emit kept rows only (rest zeroed by the pass at the top; those stores
    // are drained by the barriers above)
    for (int i = tid; i < M; i += 256) {
        if ((keepw[i >> 6] >> (i & 63)) & 1ull) {
            float4 bb = gbox[i];
            out[i * 5 + 0] = gss[i];
            out[i * 5 + 1] = bb.x;
            out[i * 5 + 2] = bb.y;
            out[i * 5 + 3] = __fsub_rn(bb.z, bb.x);
            out[i * 5 + 4] = __fsub_rn(bb.w, bb.y);
            out[5 * NB + i] = 1.0f;
        }
    }
}

extern "C" void kernel_launch(void* const* d_in, const int* in_sizes, int n_in,
                              void* d_out, int out_size, void* d_ws, size_t ws_size,
                              hipStream_t stream) {
    const float* x = (const float*)d_in[0];
    float* out = (float*)d_out;

    char* ws = (char*)d_ws;
    int* counter = (int*)ws;
    float*  gss  = (float*)(ws + 16);
    float4* gbox = (float4*)(ws + 16 + (size_t)4 * NB);
    u64*    adjT = (u64*)(ws + 16 + (size_t)4 * NB + (size_t)16 * NB);
    u64*    skeys = (u64*)((char*)adjT + (size_t)16384 * 8);
    const size_t NEEDED = 16 + (size_t)4 * NB + (size_t)16 * NB
                        + (size_t)16384 * 8 + (size_t)8 * NB;      // 389,136
    int ws_ok = (ws_size >= NEEDED) ? 1 : 0;

    k_front<<<64, 256, 0, stream>>>(x, gss, gbox, skeys, counter, adjT, ws_ok);
    k_sweep<<<1, 256, 0, stream>>>(x, out, gss, gbox, skeys, counter, adjT, ws_ok);
}